// Round 1
// baseline (153.580 us; speedup 1.0000x reference)
//
#include <hip/hip_runtime.h>
#include <stdint.h>

typedef float  f32x4 __attribute__((ext_vector_type(4)));
typedef short  s16x8 __attribute__((ext_vector_type(8)));
typedef unsigned short u16;
typedef unsigned int   u32;

#define MFMA16(a,b,c) __builtin_amdgcn_mfma_f32_16x16x32_bf16((a),(b),(c),0,0,0)

__device__ __forceinline__ u16 f2bf(float f){
  u32 u = __float_as_uint(f);
  return (u16)((u + 0x7fffu + ((u >> 16) & 1u)) >> 16);   // RNE
}
__device__ __forceinline__ float bf2f(u16 h){ return __uint_as_float(((u32)h) << 16); }
__device__ __forceinline__ f32x4 f4zero(){ f32x4 z; z[0]=0.f; z[1]=0.f; z[2]=0.f; z[3]=0.f; return z; }

// async global->LDS, 16B per lane; LDS dest is wave-uniform base + lane*16
__device__ __forceinline__ void async16(const void* g, void* l){
  __builtin_amdgcn_global_load_lds(
      (const __attribute__((address_space(1))) unsigned int*)g,
      (__attribute__((address_space(3))) unsigned int*)l, 16, 0, 0);
}

// ---------------------------------------------------------------------------
// K1: split x -> xh/xl (bf16 hi/lo), build Xt (bf16 x transposed per batch),
//     and (block 0/1) prep wr^T hi/lo and w1^T bf16.
// ---------------------------------------------------------------------------
__global__ __launch_bounds__(256) void k_prep(
    const float* __restrict__ x, const float* __restrict__ wr, const float* __restrict__ w1,
    u16* __restrict__ xh, u16* __restrict__ xl, u16* __restrict__ Xt,
    u16* __restrict__ wrth, u16* __restrict__ wrtl, u16* __restrict__ w1t)
{
  __shared__ float xs[16][132];
  const int tid = threadIdx.x, bid = blockIdx.x;
  const long base = (long)bid * 2048;          // 16 rows * 128
#pragma unroll
  for (int k = 0; k < 8; k++){
    int idx = tid + k*256;
    float v = x[base + idx];
    xs[idx>>7][idx&127] = v;
    u16 h = f2bf(v);
    xh[base+idx] = h;
    xl[base+idx] = f2bf(v - bf2f(h));
  }
  __syncthreads();
  const int b  = bid >> 7;                     // 128 blocks per batch
  const int n0 = (bid & 127) * 16;
  const int nn = tid & 15, d0 = tid >> 4;
#pragma unroll
  for (int d = 0; d < 8; d++){
    int dd = d0 + d*16;
    Xt[(long)b*262144 + (long)dd*2048 + n0 + nn] = f2bf(xs[nn][dd]);
  }
  if (bid == 0){
#pragma unroll
    for (int k = 0; k < 64; k++){
      int idx = tid + k*256;
      int g = idx >> 7, f = idx & 127;
      float v = wr[f*128 + g];                 // wrT[g][f] = wr[f][g]
      u16 h = f2bf(v);
      wrth[idx] = h;
      wrtl[idx] = f2bf(v - bf2f(h));
    }
  } else if (bid == 1){
#pragma unroll
    for (int k = 0; k < 64; k++){
      int idx = tid + k*256;
      int c = idx >> 7, f = idx & 127;
      w1t[idx] = f2bf(w1[f*128 + c]);          // w1T[c][f] = w1[f][c]
    }
  }
}

// ---------------------------------------------------------------------------
// K2: y = x @ wr via 3-term split bf16 MFMA; write yh/yl (bf16 hi/lo)
// ---------------------------------------------------------------------------
__global__ __launch_bounds__(128, 2) void k_ygemm(
    const u16* __restrict__ xh, const u16* __restrict__ xl,
    const u16* __restrict__ wrth, const u16* __restrict__ wrtl,
    u16* __restrict__ yh, u16* __restrict__ yl)
{
  __shared__ u16 sbh[16384], sbl[16384];       // [c][f] bf16, XOR-swizzled
  const int tid = threadIdx.x, bid = blockIdx.x;
#pragma unroll
  for (int k = 0; k < 16; k++){
    int off = (tid + k*128) * 16;
    int row = off >> 8;
    int dst = off ^ ((row & 7) << 4);
    *(s16x8*)((char*)sbh + dst) = *(const s16x8*)((const char*)wrth + off);
    *(s16x8*)((char*)sbl + dst) = *(const s16x8*)((const char*)wrtl + off);
  }
  __syncthreads();
  const int w = tid >> 6, lane = tid & 63, lr = lane & 15, g = lane >> 4;
  const long rowbase = (long)bid*64 + w*32;
  s16x8 ah[2][4], al[2][4];
#pragma unroll
  for (int rh = 0; rh < 2; rh++)
#pragma unroll
    for (int kc = 0; kc < 4; kc++){
      long r = rowbase + rh*16 + lr;
      ah[rh][kc] = *(const s16x8*)(xh + r*128 + kc*32 + g*8);
      al[rh][kc] = *(const s16x8*)(xl + r*128 + kc*32 + g*8);
    }
  f32x4 acc[2][8];
#pragma unroll
  for (int rh = 0; rh < 2; rh++)
#pragma unroll
    for (int cg = 0; cg < 8; cg++) acc[rh][cg] = f4zero();
  const int swz = (lr & 7) << 4;
#pragma unroll
  for (int cg = 0; cg < 8; cg++){
    const int rowt = (cg*16 + lr) * 256;
#pragma unroll
    for (int kc = 0; kc < 4; kc++){
      int boff = rowt + ((kc*64 + g*16) ^ swz);
      s16x8 bh = *(const s16x8*)((const char*)sbh + boff);
      s16x8 bl = *(const s16x8*)((const char*)sbl + boff);
#pragma unroll
      for (int rh = 0; rh < 2; rh++){
        acc[rh][cg] = MFMA16(ah[rh][kc], bh, acc[rh][cg]);
        acc[rh][cg] = MFMA16(al[rh][kc], bh, acc[rh][cg]);
        acc[rh][cg] = MFMA16(ah[rh][kc], bl, acc[rh][cg]);
      }
    }
  }
#pragma unroll
  for (int rh = 0; rh < 2; rh++)
#pragma unroll
    for (int cg = 0; cg < 8; cg++)
#pragma unroll
      for (int r = 0; r < 4; r++){
        long q = rowbase + rh*16 + 4*g + r;    // C-layout: row=(l>>4)*4+reg
        int  c = cg*16 + lr;                   //           col=l&15
        float v = acc[rh][cg][r];
        u16 h = f2bf(v);
        yh[q*128 + c] = h;
        yl[q*128 + c] = f2bf(v - bf2f(h));
      }
}

// ---------------------------------------------------------------------------
// K3: fused flash  S = y x^T (3-term split) -> online softmax -> O += P X
//     grid = 128 q-blocks * KS kv-splits; 4 warps * 32 q-rows per block
// ---------------------------------------------------------------------------
__global__ __launch_bounds__(256, 2) void k_flash(
    const u16* __restrict__ xh, const u16* __restrict__ xl, const u16* __restrict__ Xt,
    const u16* __restrict__ yh, const u16* __restrict__ yl,
    u16* __restrict__ A1bf,
    float* __restrict__ Opart, float* __restrict__ mpart, float* __restrict__ lpart,
    int KS)
{
  __shared__ u16 sxh[2][4096], sxl[2][4096], sxt[2][4096];  // 32x128 tiles (xt: 128x32)
  __shared__ u16 sP[4][1280];                               // per-warp P scratch [32][40]
  const int tid = threadIdx.x, bid = blockIdx.x;
  const int qb = bid & 127, s = bid >> 7;
  const int b  = qb >> 4;
  const int nspan = 2048 / KS;
  const int kv0   = s * nspan;
  const int ntiles = nspan / 32;
  const int w = tid >> 6, lane = tid & 63, lr = lane & 15, g = lane >> 4;
  const long qrow = (long)qb*128 + w*32;       // global q-row base of this warp

  // hoisted Y fragments (A-operands), hi/lo
  s16x8 ayh[2][4], ayl[2][4];
#pragma unroll
  for (int rh = 0; rh < 2; rh++)
#pragma unroll
    for (int kc = 0; kc < 4; kc++){
      long r = qrow + rh*16 + lr;
      ayh[rh][kc] = *(const s16x8*)(yh + r*128 + kc*32 + g*8);
      ayl[rh][kc] = *(const s16x8*)(yl + r*128 + kc*32 + g*8);
    }

  f32x4 o[2][8];
#pragma unroll
  for (int rh = 0; rh < 2; rh++)
#pragma unroll
    for (int dg = 0; dg < 8; dg++) o[rh][dg] = f4zero();
  float mrun[2][4], lrun[2][4];
#pragma unroll
  for (int rh = 0; rh < 2; rh++)
#pragma unroll
    for (int r = 0; r < 4; r++){ mrun[rh][r] = -1e30f; lrun[rh][r] = 0.f; }

  const char* gxh = (const char*)xh + ((long)b*2048 + kv0)*256;
  const char* gxl = (const char*)xl + ((long)b*2048 + kv0)*256;
  const char* gxt = (const char*)Xt + (long)b*524288 + (long)kv0*2;

  auto stage = [&](int bufi, int t){
#pragma unroll
    for (int c2 = 0; c2 < 2; c2++){
      int chunk = w + c2*4;
      int off = chunk*1024 + lane*16;
      int row = off >> 8;
      int swo = off ^ ((row & 7) << 4);        // pre-swizzled global source (m173)
      async16(gxh + (long)t*8192 + swo, &sxh[bufi][chunk*512]);
      async16(gxl + (long)t*8192 + swo, &sxl[bufi][chunk*512]);
      async16(gxt + (long)t*64 + (long)(off>>6)*4096 + (off & 63), &sxt[bufi][chunk*512]);
    }
  };

  stage(0, 0);
  __syncthreads();

  const int swzm = (lr & 7) << 4;
  for (int t = 0; t < ntiles; t++){
    const int cur = t & 1;
    if (t + 1 < ntiles) stage(cur ^ 1, t + 1);
    const char* pxh = (const char*)&sxh[cur][0];
    const char* pxl = (const char*)&sxl[cur][0];

    // ---- S tile [32q x 32kv], 3-term hi/lo split ----
    f32x4 sacc[2][2];
#pragma unroll
    for (int rh = 0; rh < 2; rh++){ sacc[rh][0] = f4zero(); sacc[rh][1] = f4zero(); }
#pragma unroll
    for (int ch = 0; ch < 2; ch++){
      const int rowt = (ch*16 + lr) * 256;
#pragma unroll
      for (int kc = 0; kc < 4; kc++){
        const int boff = rowt + ((kc*64 + g*16) ^ swzm);
        s16x8 bh = *(const s16x8*)(pxh + boff);
        s16x8 bl = *(const s16x8*)(pxl + boff);
#pragma unroll
        for (int rh = 0; rh < 2; rh++){
          sacc[rh][ch] = MFMA16(ayh[rh][kc], bh, sacc[rh][ch]);
          sacc[rh][ch] = MFMA16(ayl[rh][kc], bh, sacc[rh][ch]);
          sacc[rh][ch] = MFMA16(ayh[rh][kc], bl, sacc[rh][ch]);
        }
      }
    }

    // ---- online softmax (rows spread over l&15; 4-step xor reduce) ----
#pragma unroll
    for (int rh = 0; rh < 2; rh++){
      float cm[4];
#pragma unroll
      for (int r = 0; r < 4; r++){
        cm[r] = fmaxf(sacc[rh][0][r], sacc[rh][1][r]);
        cm[r] = fmaxf(cm[r], __shfl_xor(cm[r], 1, 64));
        cm[r] = fmaxf(cm[r], __shfl_xor(cm[r], 2, 64));
        cm[r] = fmaxf(cm[r], __shfl_xor(cm[r], 4, 64));
        cm[r] = fmaxf(cm[r], __shfl_xor(cm[r], 8, 64));
      }
      float sc[4];
#pragma unroll
      for (int r = 0; r < 4; r++){
        float mn = fmaxf(mrun[rh][r], cm[r]);
        sc[r] = __expf(mrun[rh][r] - mn);
        mrun[rh][r] = mn;
      }
#pragma unroll
      for (int dg = 0; dg < 8; dg++)
#pragma unroll
        for (int r = 0; r < 4; r++) o[rh][dg][r] *= sc[r];
      float p0[4], p1[4], rs[4];
#pragma unroll
      for (int r = 0; r < 4; r++){
        p0[r] = __expf(sacc[rh][0][r] - mrun[rh][r]);
        p1[r] = __expf(sacc[rh][1][r] - mrun[rh][r]);
        rs[r] = p0[r] + p1[r];
        rs[r] += __shfl_xor(rs[r], 1, 64);
        rs[r] += __shfl_xor(rs[r], 2, 64);
        rs[r] += __shfl_xor(rs[r], 4, 64);
        rs[r] += __shfl_xor(rs[r], 8, 64);
        lrun[rh][r] = lrun[rh][r]*sc[r] + rs[r];
      }
      // P -> LDS scratch, row-major [32][40] (DS ops are wave-ordered)
#pragma unroll
      for (int r = 0; r < 4; r++){
        int q = rh*16 + 4*g + r;
        sP[w][q*40 + lr]      = f2bf(p0[r]);
        sP[w][q*40 + 16 + lr] = f2bf(p1[r]);
      }
    }

    // ---- O += P @ Xtile  (A from P scratch, B from transposed x tile) ----
    s16x8 pa0 = *(const s16x8*)(&sP[w][lr*40 + g*8]);
    s16x8 pa1 = *(const s16x8*)(&sP[w][(16+lr)*40 + g*8]);
#pragma unroll
    for (int dg = 0; dg < 8; dg++){
      s16x8 bx = *(const s16x8*)(&sxt[cur][(dg*16 + lr)*32 + g*8]);
      o[0][dg] = MFMA16(pa0, bx, o[0][dg]);
      o[1][dg] = MFMA16(pa1, bx, o[1][dg]);
    }
    __syncthreads();   // drains prefetch (vmcnt 0) + guards buffer reuse
  }

  // ---- epilogue ----
  if (KS == 1){
#pragma unroll
    for (int rh = 0; rh < 2; rh++)
#pragma unroll
      for (int dg = 0; dg < 8; dg++)
#pragma unroll
        for (int r = 0; r < 4; r++){
          long q = qrow + rh*16 + 4*g + r;
          A1bf[q*128 + dg*16 + lr] = f2bf(o[rh][dg][r] / lrun[rh][r]);
        }
  } else {
    const long pid = bid;
#pragma unroll
    for (int rh = 0; rh < 2; rh++)
#pragma unroll
      for (int dg = 0; dg < 8; dg++)
#pragma unroll
        for (int r = 0; r < 4; r++){
          int lq = w*32 + rh*16 + 4*g + r;
          Opart[pid*16384 + (long)lq*128 + dg*16 + lr] = o[rh][dg][r];
        }
    if (lr == 0){
#pragma unroll
      for (int rh = 0; rh < 2; rh++)
#pragma unroll
        for (int r = 0; r < 4; r++){
          int lq = w*32 + rh*16 + 4*g + r;
          mpart[pid*128 + lq] = mrun[rh][r];
          lpart[pid*128 + lq] = lrun[rh][r];
        }
    }
  }
}

// ---------------------------------------------------------------------------
// K4: merge kv-split partials -> normalized A1 (bf16)
// ---------------------------------------------------------------------------
__global__ __launch_bounds__(256) void k_merge(
    const float* __restrict__ Opart, const float* __restrict__ mpart, const float* __restrict__ lpart,
    u16* __restrict__ A1bf, int KS)
{
  const int tid = threadIdx.x, bid = blockIdx.x;
  const long R = (long)bid*2 + (tid >> 7);
  const int d = tid & 127;
  const int qb = (int)(R >> 7), r = (int)(R & 127);
  float m = -1e30f;
  for (int s = 0; s < KS; s++) m = fmaxf(m, mpart[(long)(s*128 + qb)*128 + r]);
  float acc = 0.f, ls = 0.f;
  for (int s = 0; s < KS; s++){
    long pid = s*128 + qb;
    float wgt = __expf(mpart[pid*128 + r] - m);
    ls  += lpart[pid*128 + r] * wgt;
    acc += Opart[pid*16384 + (long)r*128 + d] * wgt;
  }
  A1bf[R*128 + d] = f2bf(acc / ls);
}

// ---------------------------------------------------------------------------
// K5: x1 = relu(A1 @ w1 + x)  (bf16 MFMA, fp32 out)
// ---------------------------------------------------------------------------
__global__ __launch_bounds__(128, 2) void k_layer1(
    const u16* __restrict__ A1bf, const u16* __restrict__ w1t,
    const float* __restrict__ x, float* __restrict__ x1)
{
  __shared__ u16 sb[16384];
  const int tid = threadIdx.x, bid = blockIdx.x;
#pragma unroll
  for (int k = 0; k < 16; k++){
    int off = (tid + k*128)*16;
    int row = off >> 8;
    *(s16x8*)((char*)sb + (off ^ ((row & 7) << 4))) = *(const s16x8*)((const char*)w1t + off);
  }
  __syncthreads();
  const int w = tid >> 6, lane = tid & 63, lr = lane & 15, g = lane >> 4;
  const long rowbase = (long)bid*64 + w*32;
  s16x8 aa[2][4];
#pragma unroll
  for (int rh = 0; rh < 2; rh++)
#pragma unroll
    for (int kc = 0; kc < 4; kc++)
      aa[rh][kc] = *(const s16x8*)(A1bf + (rowbase + rh*16 + lr)*128 + kc*32 + g*8);
  f32x4 acc[2][8];
#pragma unroll
  for (int rh = 0; rh < 2; rh++)
#pragma unroll
    for (int cg = 0; cg < 8; cg++) acc[rh][cg] = f4zero();
  const int swz = (lr & 7) << 4;
#pragma unroll
  for (int cg = 0; cg < 8; cg++){
    const int rowt = (cg*16 + lr)*256;
#pragma unroll
    for (int kc = 0; kc < 4; kc++){
      s16x8 bb = *(const s16x8*)((const char*)sb + rowt + ((kc*64 + g*16) ^ swz));
#pragma unroll
      for (int rh = 0; rh < 2; rh++)
        acc[rh][cg] = MFMA16(aa[rh][kc], bb, acc[rh][cg]);
    }
  }
#pragma unroll
  for (int rh = 0; rh < 2; rh++)
#pragma unroll
    for (int cg = 0; cg < 8; cg++)
#pragma unroll
      for (int r = 0; r < 4; r++){
        long q = rowbase + rh*16 + 4*g + r;
        int  c = cg*16 + lr;
        float v = acc[rh][cg][r] + x[q*128 + c];
        x1[q*128 + c] = fmaxf(v, 0.f);
      }
}

// ---------------------------------------------------------------------------
// K6: exact fp32 row-0 logits  S0[b,m] = (x[b,0,:] @ wr) . x[b,m,:]
// ---------------------------------------------------------------------------
__global__ __launch_bounds__(256) void k_s0(
    const float* __restrict__ x, const float* __restrict__ wr,
    float* __restrict__ S0, float* __restrict__ maxpart)
{
  __shared__ float x0s[128];
  __shared__ float ys[128];
  __shared__ float red[256];
  const int tid = threadIdx.x, bid = blockIdx.x;
  const int b = bid >> 3, j = bid & 7;
  if (tid < 128) x0s[tid] = x[(long)b*262144 + tid];
  __syncthreads();
  if (tid < 128){
    float a = 0.f;
    for (int f = 0; f < 128; f++) a += x0s[f] * wr[f*128 + tid];
    ys[tid] = a;
  }
  __syncthreads();
  const int m = j*256 + tid;
  const float4* xr = (const float4*)(x + ((long)b*2048 + m)*128);
  const float4* yv = (const float4*)ys;
  float acc = 0.f;
#pragma unroll
  for (int f = 0; f < 32; f++){
    float4 a = xr[f], c = yv[f];
    acc += a.x*c.x + a.y*c.y + a.z*c.z + a.w*c.w;
  }
  S0[b*2048 + m] = acc;
  red[tid] = acc;
  __syncthreads();
  for (int sft = 128; sft > 0; sft >>= 1){
    if (tid < sft) red[tid] = fmaxf(red[tid], red[tid + sft]);
    __syncthreads();
  }
  if (tid == 0) maxpart[bid] = red[0];
}

// K7: row-0 softmax (fp32 exact)
__global__ __launch_bounds__(256) void k_r0(
    const float* __restrict__ S0, const float* __restrict__ maxpart, float* __restrict__ R0)
{
  __shared__ float red[256];
  const int tid = threadIdx.x, b = blockIdx.x;
  float M = -1e30f;
#pragma unroll
  for (int jj = 0; jj < 8; jj++) M = fmaxf(M, maxpart[b*8 + jj]);
  float sv[8]; float se = 0.f;
#pragma unroll
  for (int k = 0; k < 8; k++){
    sv[k] = __expf(S0[b*2048 + tid + k*256] - M);
    se += sv[k];
  }
  red[tid] = se;
  __syncthreads();
  for (int sft = 128; sft > 0; sft >>= 1){
    if (tid < sft) red[tid] += red[tid + sft];
    __syncthreads();
  }
  float inv = 1.f / red[0];
#pragma unroll
  for (int k = 0; k < 8; k++) R0[b*2048 + tid + k*256] = sv[k]*inv;
}

// K8: A2 partials  A2p[b,j,:] = sum_{m in chunk j} R0[b,m] * x1[b,m,:]
__global__ __launch_bounds__(256) void k_a2(
    const float* __restrict__ R0, const float* __restrict__ x1, float* __restrict__ A2p)
{
  __shared__ float red[128];
  const int tid = threadIdx.x, bid = blockIdx.x;
  const int b = bid >> 3, j = bid & 7;
  const int d = tid & 127, h = tid >> 7;
  float acc = 0.f;
  for (int mi = j*256 + h; mi < j*256 + 256; mi += 2)
    acc += R0[b*2048 + mi] * x1[((long)b*2048 + mi)*128 + d];
  if (h == 1) red[d] = acc;
  __syncthreads();
  if (h == 0) A2p[(long)bid*128 + d] = acc + red[d];
}

// K9: out = relu(A2 @ w2 + x1[:,0,:])
__global__ __launch_bounds__(256) void k_out(
    const float* __restrict__ A2p, const float* __restrict__ w2,
    const float* __restrict__ x1, float* __restrict__ out)
{
  __shared__ float a2s[2][128];
  const int tid = threadIdx.x, bid = blockIdx.x;
  const int b0 = bid*2;
  {
    int which = tid >> 7, f = tid & 127;
    float s = 0.f;
#pragma unroll
    for (int jj = 0; jj < 8; jj++) s += A2p[(long)((b0 + which)*8 + jj)*128 + f];
    a2s[which][f] = s;
  }
  __syncthreads();
  const int which = tid >> 7, d = tid & 127;
  const int b = b0 + which;
  float acc = x1[(long)b*262144 + d];
  for (int f = 0; f < 128; f++)
    acc += a2s[which][f] * w2[f*128 + d];
  out[b*128 + d] = fmaxf(acc, 0.f);
}

// ---------------------------------------------------------------------------
extern "C" void kernel_launch(void* const* d_in, const int* in_sizes, int n_in,
                              void* d_out, int out_size, void* d_ws, size_t ws_size,
                              hipStream_t stream)
{
  const float* x  = (const float*)d_in[0];
  const float* w1 = (const float*)d_in[1];
  const float* w2 = (const float*)d_in[2];
  const float* wr = (const float*)d_in[3];
  float* out = (float*)d_out;
  char* ws = (char*)d_ws;

  u16*   xh      = (u16*)  (ws + 0);
  u16*   xl      = (u16*)  (ws + 4194304);
  u16*   Xt      = (u16*)  (ws + 8388608);
  u16*   yh      = (u16*)  (ws + 12582912);
  u16*   yl      = (u16*)  (ws + 16777216);
  u16*   wrth    = (u16*)  (ws + 20971520);
  u16*   wrtl    = (u16*)  (ws + 21004288);
  u16*   w1t     = (u16*)  (ws + 21037056);
  u16*   A1bf    = (u16*)  (ws + 21069824);
  float* R0      = (float*)(ws + 25264128);
  float* S0      = (float*)(ws + 25329664);
  float* maxpart = (float*)(ws + 25395200);
  float* A2p     = (float*)(ws + 25396224);
  float* x1      = (float*)(ws + 25428992);
  float* mpart   = (float*)(ws + 33817600);
  float* lpart   = (float*)(ws + 34079744);
  float* Opart   = (float*)(ws + 34341888);

  // pick kv-split by available workspace (Opart = KS * 8 MB)
  int KS = 4;
  const size_t base_need = 34341888ull;
  while (KS > 1 && base_need + (size_t)KS*8388608ull > ws_size) KS >>= 1;

  k_prep  <<<1024, 256, 0, stream>>>(x, wr, w1, xh, xl, Xt, wrth, wrtl, w1t);
  k_ygemm <<<256, 128, 0, stream>>>(xh, xl, wrth, wrtl, yh, yl);
  k_flash <<<128*KS, 256, 0, stream>>>(xh, xl, Xt, yh, yl, A1bf, Opart, mpart, lpart, KS);
  if (KS > 1)
    k_merge <<<8192, 256, 0, stream>>>(Opart, mpart, lpart, A1bf, KS);
  k_layer1<<<256, 128, 0, stream>>>(A1bf, w1t, x, x1);
  k_s0    <<<64, 256, 0, stream>>>(x, wr, S0, maxpart);
  k_r0    <<<8, 256, 0, stream>>>(S0, maxpart, R0);
  k_a2    <<<64, 256, 0, stream>>>(R0, x1, A2p);
  k_out   <<<4, 256, 0, stream>>>(A2p, w2, x1, out);
}